// Round 16
// baseline (174.342 us; speedup 1.0000x reference)
//
#include <hip/hip_runtime.h>
#include <hip/hip_fp16.h>
#include <math.h>

#define HH 32
#define WW 32
#define HWSZ 1024      // H*W
#define CC 384
#define NHEAD 12
#define NGROUP 6
#define HC 32
#define GC 64
#define NS 1024        // n_sample
#define ATTN_SCALE 0.17677669529663687f  // 32^-0.5

typedef _Float16 half8_t __attribute__((ext_vector_type(8)));
typedef _Float16 half4_t __attribute__((ext_vector_type(4)));
typedef _Float16 half2_t __attribute__((ext_vector_type(2)));
typedef float    f4_t    __attribute__((ext_vector_type(4)));

// ---------------------------------------------------------------------------
// MFMA GEMM, fp32 out: Y[b,o,n] = sum_c W[o,c] X[b,c,n] + bias[o].
// W pure f16; X pure f16 (XLO=0, q-proj) or f16 hi/lo (XLO=1, o-proj).
// R16 retile: 32x32 block tile, 4 waves each an INDEPENDENT 16x16 output
// tile (wm=w>>1 m-half, wn=w&1 n-half). Grid 768 blocks = 3072 waves
// (2x R15's 1536) for latency hiding; staging per block halved.
// ---------------------------------------------------------------------------
template<int XLO>
__global__ __launch_bounds__(256) void gemm_wx(
    const float* __restrict__ W, const float* __restrict__ bias,
    const float* __restrict__ X, float* __restrict__ Y)
{
    const int bz = blockIdx.z;
    const int tm = blockIdx.y * 32;
    const int tn = blockIdx.x * 32;
    const int tid = threadIdx.x;
    const int w = tid >> 6, lane = tid & 63;
    const int quad = lane >> 4, lcol = lane & 15;
    const int wm = w >> 1, wn = w & 1;

    __shared__ _Float16 sWh[32][40];
    __shared__ _Float16 sXh[32][40];
    __shared__ _Float16 sXl[XLO ? 32 : 1][40];

    const float* Xb = X + (size_t)bz * CC * 1024;
    float* Yb = Y + (size_t)bz * CC * 1024;

    f4_t acc = {0.f, 0.f, 0.f, 0.f};

    for (int k0 = 0; k0 < CC; k0 += 32) {
        {   // W: 32m x 32k, one float4 per thread
            int m = tid >> 3, kc = (tid & 7) * 4;
            float4 wv = *(const float4*)&W[(size_t)(tm + m) * CC + k0 + kc];
            half4_t h; h[0] = (_Float16)wv.x; h[1] = (_Float16)wv.y;
            h[2] = (_Float16)wv.z; h[3] = (_Float16)wv.w;
            *(half4_t*)&sWh[m][kc] = h;
        }
        {   // X: 32k x 32n -> [n][k], 4 scalar loads per thread
            int k = tid >> 3, nj = tid & 7;
            const float* xr = &Xb[(size_t)(k0 + k) * 1024 + tn + nj];
#pragma unroll
            for (int i = 0; i < 4; ++i) {
                float v = xr[8 * i];
                _Float16 h = (_Float16)v;
                sXh[nj + 8 * i][k] = h;
                if (XLO) sXl[nj + 8 * i][k] = (_Float16)(v - (float)h);
            }
        }
        __syncthreads();

        half8_t Ah = *(const half8_t*)&sWh[wm * 16 + lcol][quad * 8];
        half8_t Bh = *(const half8_t*)&sXh[wn * 16 + lcol][quad * 8];
        acc = __builtin_amdgcn_mfma_f32_16x16x32_f16(Ah, Bh, acc, 0, 0, 0);
        if (XLO) {
            half8_t Bl = *(const half8_t*)&sXl[wn * 16 + lcol][quad * 8];
            acc = __builtin_amdgcn_mfma_f32_16x16x32_f16(Ah, Bl, acc, 0, 0, 0);
        }
        __syncthreads();
    }

#pragma unroll
    for (int r = 0; r < 4; ++r) {
        int m0 = tm + wm * 16 + quad * 4 + r;
        Yb[(size_t)m0 * 1024 + tn + wn * 16 + lcol] = acc[r] + bias[m0];
    }
}

// ---------------------------------------------------------------------------
// FUSED MFMA K+V projection (pure f16), R16 retile: 32x32 block tile, 4
// waves each own (wm=hc-half, wn=n-half) and compute 1 K-MFMA + 1 V-MFMA
// per k-iter.  Grid (32 n-tiles, 12 heads, 2 batches) = 768 blocks.
//   K: D[n][hc] = X^T·Wk^T -> khT [bh][n][hc]
//   V: D[hc][n] = Wv·X     -> vhb [bh][hc][n]
// ---------------------------------------------------------------------------
__global__ __launch_bounds__(256) void gemm_kv_fused(
    const float* __restrict__ Wk, const float* __restrict__ bk,
    const float* __restrict__ Wv, const float* __restrict__ bv,
    const float* __restrict__ X,
    _Float16* __restrict__ khT, _Float16* __restrict__ vhb)
{
    const int bz = blockIdx.z;
    const int head = blockIdx.y;
    const int tm = head * 32;
    const int tn = blockIdx.x * 32;
    const int tid = threadIdx.x;
    const int w = tid >> 6, lane = tid & 63;
    const int quad = lane >> 4, lcol = lane & 15;
    const int wm = w >> 1, wn = w & 1;
    const int bh = bz * 12 + head;

    __shared__ _Float16 sWk[32][40], sWv[32][40];
    __shared__ _Float16 sXh[32][40];

    const float* Xb = X + (size_t)bz * CC * 1024;

    f4_t ak = {0.f, 0.f, 0.f, 0.f};
    f4_t av = {0.f, 0.f, 0.f, 0.f};

    for (int k0 = 0; k0 < CC; k0 += 32) {
        {   // Wk + Wv: one float4 each per thread
            int m = tid >> 3, kc = (tid & 7) * 4;
            float4 wkv = *(const float4*)&Wk[(size_t)(tm + m) * CC + k0 + kc];
            float4 wvv = *(const float4*)&Wv[(size_t)(tm + m) * CC + k0 + kc];
            half4_t hk; hk[0] = (_Float16)wkv.x; hk[1] = (_Float16)wkv.y;
            hk[2] = (_Float16)wkv.z; hk[3] = (_Float16)wkv.w;
            half4_t hv; hv[0] = (_Float16)wvv.x; hv[1] = (_Float16)wvv.y;
            hv[2] = (_Float16)wvv.z; hv[3] = (_Float16)wvv.w;
            *(half4_t*)&sWk[m][kc] = hk;
            *(half4_t*)&sWv[m][kc] = hv;
        }
        {   // X: 32k x 32n -> [n][k]
            int k = tid >> 3, nj = tid & 7;
            const float* xr = &Xb[(size_t)(k0 + k) * 1024 + tn + nj];
#pragma unroll
            for (int i = 0; i < 4; ++i)
                sXh[nj + 8 * i][k] = (_Float16)xr[8 * i];
        }
        __syncthreads();

        half8_t Xf = *(const half8_t*)&sXh[wn * 16 + lcol][quad * 8];
        half8_t Kf = *(const half8_t*)&sWk[wm * 16 + lcol][quad * 8];
        half8_t Vf = *(const half8_t*)&sWv[wm * 16 + lcol][quad * 8];
        ak = __builtin_amdgcn_mfma_f32_16x16x32_f16(Xf, Kf, ak, 0, 0, 0);   // D[n][hc]
        av = __builtin_amdgcn_mfma_f32_16x16x32_f16(Vf, Xf, av, 0, 0, 0);   // D[hc][n]
        __syncthreads();
    }

    {   // K epilogue: rows = n, cols = hc
        int hc = wm * 16 + lcol;
        float bkv = bk[tm + hc];
#pragma unroll
        for (int r = 0; r < 4; ++r) {
            int n = tn + wn * 16 + quad * 4 + r;
            khT[((size_t)bh * 1024 + n) * 32 + hc] = (_Float16)(ak[r] + bkv);
        }
    }
    {   // V epilogue: rows = hc, cols = n
        int n = tn + wn * 16 + lcol;
#pragma unroll
        for (int r = 0; r < 4; ++r) {
            int hc0 = wm * 16 + quad * 4 + r;
            vhb[((size_t)bh * 32 + hc0) * 1024 + n] = (_Float16)(av[r] + bv[tm + hc0]);
        }
    }
}

// ---------------------------------------------------------------------------
// Depthwise 7x7 conv on q viewed as [12, 64, 32, 32]; zero pad 3.
// ---------------------------------------------------------------------------
__global__ __launch_bounds__(256) void dwconv_kernel(
    const float* __restrict__ q, const float* __restrict__ dww,
    const float* __restrict__ dwb, float* __restrict__ oconv)
{
    const int bc = blockIdx.x;
    const int bg = bc >> 6, c = bc & 63;
    const int b = bg / 6, g = bg % 6;
    const float* plane = q + ((size_t)b * CC + g * 64 + c) * 1024;

    __shared__ float sp[1024];
    __shared__ float sw[49];
    const int tid = threadIdx.x;
    for (int i = tid; i < 1024; i += 256) sp[i] = plane[i];
    if (tid < 49) sw[tid] = dww[c * 49 + tid];
    __syncthreads();

    const float bias = dwb[c];
    for (int i = tid; i < 1024; i += 256) {
        int y = i >> 5, x = i & 31;
        float s = 0.f;
#pragma unroll
        for (int ky = 0; ky < 7; ++ky) {
            int yy = y + ky - 3;
            if (yy < 0 || yy > 31) continue;
#pragma unroll
            for (int kx = 0; kx < 7; ++kx) {
                int xx = x + kx - 3;
                if (xx < 0 || xx > 31) continue;
                s += sp[yy * 32 + xx] * sw[ky * 7 + kx];
            }
        }
        oconv[(size_t)bc * 1024 + i] = s + bias;
    }
}

// ---------------------------------------------------------------------------
// FUSED offset + sample, 4-way channel-split (R13 version).
// ---------------------------------------------------------------------------
__global__ __launch_bounds__(256) void offset_sample_kernel(
    const float* __restrict__ oconv, const float* __restrict__ lng,
    const float* __restrict__ lnb, const float* __restrict__ pw,
    const float* __restrict__ x, float* __restrict__ pos,
    float* __restrict__ xs)
{
    const int bg = blockIdx.y;
    const int cs = blockIdx.z;
    const int px0 = blockIdx.x * 64;
    const int t = threadIdx.x;
    const int cg = t >> 6, pl = t & 63;
    const int px = px0 + pl;
    const int b = bg / 6, g = bg % 6;

    __shared__ float red[4][64];
    __shared__ float spos[64][2];

    const float* base = oconv + ((size_t)bg * 64 + cg * 16) * 1024 + px;
    float col[16];
    float s = 0.f;
#pragma unroll
    for (int i = 0; i < 16; ++i) { col[i] = base[(size_t)i * 1024]; s += col[i]; }
    red[cg][pl] = s;
    __syncthreads();
    float mu = (red[0][pl] + red[1][pl] + red[2][pl] + red[3][pl]) * (1.f / 64.f);
    float v = 0.f;
#pragma unroll
    for (int i = 0; i < 16; ++i) { float d = col[i] - mu; v += d * d; }
    __syncthreads();
    red[cg][pl] = v;
    __syncthreads();
    float inv = rsqrtf((red[0][pl] + red[1][pl] + red[2][pl] + red[3][pl]) * (1.f / 64.f) + 1e-5f);

    float oy = 0.f, ox = 0.f;
#pragma unroll
    for (int i = 0; i < 16; ++i) {
        int c = cg * 16 + i;
        float val = (col[i] - mu) * inv * lng[c] + lnb[c];
        float gl = 0.5f * val * (1.f + erff(val * 0.70710678118654752440f));
        oy += gl * pw[c];
        ox += gl * pw[64 + c];
    }
    __syncthreads();
    red[cg][pl] = oy;
    __syncthreads();
    float oyt = red[0][pl] + red[1][pl] + red[2][pl] + red[3][pl];
    __syncthreads();
    red[cg][pl] = ox;
    __syncthreads();
    if (cg == 0) {
        float oxt = red[0][pl] + red[1][pl] + red[2][pl] + red[3][pl];
        float offy = tanhf(oyt) * (2.0f / 32.0f);
        float offx = tanhf(oxt) * (2.0f / 32.0f);
        int y = px >> 5, xx = px & 31;
        float ry = ((y + 0.5f) / 32.f) * 2.f - 1.f;
        float rx = ((xx + 0.5f) / 32.f) * 2.f - 1.f;
        float py = offy + ry, pxv = offx + rx;
        spos[pl][0] = py; spos[pl][1] = pxv;
        if (cs == 0) {
            pos[((size_t)bg * 1024 + px) * 2 + 0] = py;
            pos[((size_t)bg * 1024 + px) * 2 + 1] = pxv;
        }
    }
    __syncthreads();

    float py = spos[pl][0], pxv = spos[pl][1];
    float gx = (pxv + 1.f) * 0.5f * 31.f;
    float gy = (py + 1.f) * 0.5f * 31.f;
    float x0f = floorf(gx), y0f = floorf(gy);
    float wx = gx - x0f, wy = gy - y0f;
    int x0 = (int)x0f, y0 = (int)y0f;
    float vx0 = ((unsigned)x0 <= 31u) ? 1.f : 0.f;
    float vx1 = ((unsigned)(x0 + 1) <= 31u) ? 1.f : 0.f;
    float vy0 = ((unsigned)y0 <= 31u) ? 1.f : 0.f;
    float vy1 = ((unsigned)(y0 + 1) <= 31u) ? 1.f : 0.f;
    float w00 = (1.f - wx) * (1.f - wy) * vx0 * vy0;
    float w01 = wx * (1.f - wy) * vx1 * vy0;
    float w10 = (1.f - wx) * wy * vx0 * vy1;
    float w11 = wx * wy * vx1 * vy1;
    int xc0 = min(max(x0, 0), 31), xc1 = min(max(x0 + 1, 0), 31);
    int yc0 = min(max(y0, 0), 31), yc1 = min(max(y0 + 1, 0), 31);
    int i00 = yc0 * 32 + xc0, i01 = yc0 * 32 + xc1;
    int i10 = yc1 * 32 + xc0, i11 = yc1 * 32 + xc1;

    const int c0 = cs * 16 + cg * 4;
    const float* xb = x + ((size_t)b * CC + g * 64 + c0) * 1024;
    float* xso = xs + ((size_t)b * CC + g * 64 + c0) * 1024 + px;
#pragma unroll
    for (int i = 0; i < 4; ++i) {
        const float* plane = xb + (size_t)i * 1024;
        xso[(size_t)i * 1024] = plane[i00] * w00 + plane[i01] * w01
                              + plane[i10] * w10 + plane[i11] * w11;
    }
}

// ---------------------------------------------------------------------------
// MFMA flash attention (R15, unchanged): transposed S^T=K·Q^T, K-split 4
// waves, windowed RPE, chunk prefetch, fixed-shift softmax.
// ---------------------------------------------------------------------------
__global__ __launch_bounds__(256) void attn_mfma_kernel(
    const float* __restrict__ q, const _Float16* __restrict__ khT,
    const _Float16* __restrict__ vhb, const float* __restrict__ pos,
    const float* __restrict__ rpe, float* __restrict__ out)
{
    const int bh = blockIdx.y;
    const int b = bh / 12, head = bh % 12;
    const int bg = b * 6 + (head >> 1);
    const int mblk = blockIdx.x * 16;
    const int tid = threadIdx.x;
    const int w = tid >> 6, lane = tid & 63;
    const int quad = lane >> 4, lcol = lane & 15;

    __shared__ __align__(16) char smem[19584];
    half2_t*  srpe2 = (half2_t*)smem;
    _Float16* sqh   = (_Float16*)(smem + 8832);
    _Float16* spw   = (_Float16*)(smem + 9856) + w * (16 * 72);
    float*    cml   = (float*)(smem + 19072);
    float*    comb  = (float*)(smem + 9856);

    const float qyw = (((mblk >> 5) + 0.5f) * (1.f / 32.f)) * 2.f - 1.f;
    int r0; {
        float gy_lo = (qyw - 1.03125f) * 15.5f + 31.f;
        r0 = (int)floorf(gy_lo);
        r0 = min(max(r0, 0), 28);
    }

    const float* rp = rpe + (size_t)head * 3969;
    for (int i = tid; i < 35 * 63; i += 256) {
        int y = i / 63, xx = i - y * 63;
        int gi = (r0 + y) * 63 + xx;
        float v0 = rp[gi];
        float v1 = (xx < 62) ? rp[gi + 1] : 0.f;
        half2_t hv; hv[0] = (_Float16)v0; hv[1] = (_Float16)v1;
        srpe2[i] = hv;
    }
    {
        const float* qb = q + ((size_t)b * CC + head * 32) * 1024 + mblk;
        for (int i = tid; i < 512; i += 256) {
            int hc = i >> 4, m = i & 15;
            sqh[m * 32 + hc] = (_Float16)qb[(size_t)hc * 1024 + m];
        }
    }
    __syncthreads();

    half8_t qf = *(const half8_t*)&sqh[lcol * 32 + quad * 8];
    const float qx = (((mblk & 31) + lcol + 0.5f) * (1.f / 32.f)) * 2.f - 1.f;

    const float2* pgv = (const float2*)(pos + (size_t)bg * 2048);
    const _Float16* khb = khT + (size_t)bh * 1024 * 32;
    const _Float16* vhh = vhb + (size_t)bh * 32 * 1024;

    f4_t o0 = {0.f, 0.f, 0.f, 0.f}, o1 = {0.f, 0.f, 0.f, 0.f};
    float lsum = 0.f;

#pragma unroll 1
    for (int c = 0; c < 4; ++c) {
        const int n0 = w * 256 + c * 64;

        half8_t khv[4];
#pragma unroll
        for (int t = 0; t < 4; ++t)
            khv[t] = *(const half8_t*)&khb[(size_t)(n0 + t * 16 + lcol) * 32 + quad * 8];
        half8_t vv0[2], vv1[2];
#pragma unroll
        for (int kp = 0; kp < 2; ++kp) {
            int nb = n0 + kp * 32 + quad * 8;
            vv0[kp] = *(const half8_t*)&vhh[(size_t)lcol * 1024 + nb];
            vv1[kp] = *(const half8_t*)&vhh[(size_t)(16 + lcol) * 1024 + nb];
        }

        f4_t S[4];
#pragma unroll
        for (int t = 0; t < 4; ++t) {
            f4_t s = {0.f, 0.f, 0.f, 0.f};
            s = __builtin_amdgcn_mfma_f32_16x16x32_f16(khv[t], qf, s, 0, 0, 0);
#pragma unroll
            for (int r = 0; r < 4; ++r) {
                int key = n0 + t * 16 + quad * 4 + r;
                float2 pp = pgv[key];
                float gy = (qyw - pp.x) * 15.5f + 31.f;
                float gx = (qx  - pp.y) * 15.5f + 31.f;
                float y0f = floorf(gy), x0f = floorf(gx);
                float wy = gy - y0f, wx = gx - x0f;
                int i00 = ((int)y0f - r0) * 63 + (int)x0f;
                half2_t p0 = srpe2[i00];
                half2_t p1 = srpe2[i00 + 63];
                float r00 = (float)p0[0], r01 = (float)p0[1];
                float r10 = (float)p1[0], r11 = (float)p1[1];
                float top = r00 + (r01 - r00) * wx;
                float bot = r10 + (r11 - r10) * wx;
                s[r] = s[r] * ATTN_SCALE + top + (bot - top) * wy;
            }
            S[t] = s;
        }

#pragma unroll
        for (int t = 0; t < 4; ++t) {
            float p0 = __expf(S[t][0]);
            float p1 = __expf(S[t][1]);
            float p2 = __expf(S[t][2]);
            float p3 = __expf(S[t][3]);
            lsum += (p0 + p1) + (p2 + p3);
            half4_t h;
            h[0] = (_Float16)p0; h[1] = (_Float16)p1;
            h[2] = (_Float16)p2; h[3] = (_Float16)p3;
            *(half4_t*)&spw[lcol * 72 + t * 16 + quad * 4] = h;
        }

#pragma unroll
        for (int kp = 0; kp < 2; ++kp) {
            half8_t pb = *(const half8_t*)&spw[lcol * 72 + kp * 32 + quad * 8];
            o0 = __builtin_amdgcn_mfma_f32_16x16x32_f16(vv0[kp], pb, o0, 0, 0, 0);
            o1 = __builtin_amdgcn_mfma_f32_16x16x32_f16(vv1[kp], pb, o1, 0, 0, 0);
        }
    }

    lsum += __shfl_xor(lsum, 16);
    lsum += __shfl_xor(lsum, 32);

    __syncthreads();

    *(f4_t*)&comb[(w * 16 + lcol) * 36 + quad * 4]      = o0;
    *(f4_t*)&comb[(w * 16 + lcol) * 36 + 16 + quad * 4] = o1;
    if (quad == 0) cml[w * 16 + lcol] = lsum;
    __syncthreads();

#pragma unroll
    for (int i = 0; i < 2; ++i) {
        int idx = tid + i * 256;
        int qq = idx >> 5, hc = idx & 31;
        float L = cml[qq] + cml[16 + qq] + cml[32 + qq] + cml[48 + qq];
        float o = comb[(0 * 16 + qq) * 36 + hc]
                + comb[(1 * 16 + qq) * 36 + hc]
                + comb[(2 * 16 + qq) * 36 + hc]
                + comb[(3 * 16 + qq) * 36 + hc];
        out[((size_t)b * CC + head * 32 + hc) * 1024 + mblk + qq] = o / L;
    }
}

// ---------------------------------------------------------------------------
extern "C" void kernel_launch(void* const* d_in, const int* in_sizes, int n_in,
                              void* d_out, int out_size, void* d_ws, size_t ws_size,
                              hipStream_t stream) {
    const float* x   = (const float*)d_in[0];
    const float* Wq  = (const float*)d_in[1];
    const float* bq  = (const float*)d_in[2];
    const float* Wk  = (const float*)d_in[3];
    const float* bk  = (const float*)d_in[4];
    const float* Wv  = (const float*)d_in[5];
    const float* bv  = (const float*)d_in[6];
    const float* Wo  = (const float*)d_in[7];
    const float* bo  = (const float*)d_in[8];
    const float* dww = (const float*)d_in[9];
    const float* dwb = (const float*)d_in[10];
    const float* lng = (const float*)d_in[11];
    const float* lnb = (const float*)d_in[12];
    const float* pw  = (const float*)d_in[13];
    const float* rpe = (const float*)d_in[14];

    float* ws = (float*)d_ws;
    const size_t SZ = 786432;           // 2*384*1024 floats
    float* qbuf  = ws;
    float* xs    = ws + 1 * SZ;
    float* abuf  = ws + 2 * SZ;
    float* oconv = ws + 3 * SZ;
    _Float16* khT = (_Float16*)(ws + 4 * SZ);
    _Float16* vhb = (_Float16*)(ws + 5 * SZ);
    float* pos   = ws + 6 * SZ;

    dim3 gqo(32, 12, 2);
    gemm_wx<0><<<gqo, 256, 0, stream>>>(Wq, bq, x, qbuf);
    dwconv_kernel<<<768, 256, 0, stream>>>(qbuf, dww, dwb, oconv);
    offset_sample_kernel<<<dim3(16, 12, 4), 256, 0, stream>>>(oconv, lng, lnb, pw, x, pos, xs);
    gemm_kv_fused<<<dim3(32, 12, 2), 256, 0, stream>>>(Wk, bk, Wv, bv, xs, khT, vhb);
    attn_mfma_kernel<<<dim3(64, 24), 256, 0, stream>>>(qbuf, khT, vhb, pos, rpe, abuf);
    gemm_wx<1><<<gqo, 256, 0, stream>>>(Wo, bo, abuf, (float*)d_out);
}

// Round 17
// 166.040 us; speedup vs baseline: 1.0500x; 1.0500x over previous
//
#include <hip/hip_runtime.h>
#include <hip/hip_fp16.h>
#include <math.h>

#define HH 32
#define WW 32
#define HWSZ 1024      // H*W
#define CC 384
#define NHEAD 12
#define NGROUP 6
#define HC 32
#define GC 64
#define NS 1024        // n_sample
#define ATTN_SCALE 0.17677669529663687f  // 32^-0.5

typedef _Float16 half8_t __attribute__((ext_vector_type(8)));
typedef _Float16 half4_t __attribute__((ext_vector_type(4)));
typedef _Float16 half2_t __attribute__((ext_vector_type(2)));
typedef float    f4_t    __attribute__((ext_vector_type(4)));

// ---------------------------------------------------------------------------
// MFMA GEMM (R15 tiling — proven best): Y = W·X + b, 32m x 64n tile, BK=32.
// W pure f16; X pure f16 (XLO=0, q-proj) or f16 hi/lo (XLO=1, o-proj).
// ---------------------------------------------------------------------------
template<int XLO>
__global__ __launch_bounds__(256) void gemm_wx(
    const float* __restrict__ W, const float* __restrict__ bias,
    const float* __restrict__ X, float* __restrict__ Y)
{
    const int bz = blockIdx.z;
    const int tm = blockIdx.y * 32;
    const int tn = blockIdx.x * 64;
    const int tid = threadIdx.x;
    const int w = tid >> 6, lane = tid & 63;
    const int quad = lane >> 4, lcol = lane & 15;

    __shared__ _Float16 sWh[32][40];
    __shared__ _Float16 sXh[64][40];
    __shared__ _Float16 sXl[XLO ? 64 : 1][40];

    const float* Xb = X + (size_t)bz * CC * 1024;
    float* Yb = Y + (size_t)bz * CC * 1024;

    f4_t acc0 = {0.f, 0.f, 0.f, 0.f}, acc1 = {0.f, 0.f, 0.f, 0.f};

    for (int k0 = 0; k0 < CC; k0 += 32) {
        {
            int m = tid >> 3, k4 = (tid & 7) * 4;
            float4 wv = *(const float4*)&W[(size_t)(tm + m) * CC + k0 + k4];
            half4_t h; h[0] = (_Float16)wv.x; h[1] = (_Float16)wv.y;
            h[2] = (_Float16)wv.z; h[3] = (_Float16)wv.w;
            *(half4_t*)&sWh[m][k4] = h;
        }
        {
            int k = tid >> 3, nj = tid & 7;
            const float* xr = &Xb[(size_t)(k0 + k) * 1024 + tn + nj];
#pragma unroll
            for (int i = 0; i < 8; ++i) {
                float v = xr[8 * i];
                _Float16 h = (_Float16)v;
                sXh[nj + 8 * i][k] = h;
                if (XLO) sXl[nj + 8 * i][k] = (_Float16)(v - (float)h);
            }
        }
        __syncthreads();

        half8_t Ah0 = *(const half8_t*)&sWh[lcol][quad * 8];
        half8_t Ah1 = *(const half8_t*)&sWh[16 + lcol][quad * 8];
        half8_t Bh  = *(const half8_t*)&sXh[w * 16 + lcol][quad * 8];
        acc0 = __builtin_amdgcn_mfma_f32_16x16x32_f16(Ah0, Bh, acc0, 0, 0, 0);
        acc1 = __builtin_amdgcn_mfma_f32_16x16x32_f16(Ah1, Bh, acc1, 0, 0, 0);
        if (XLO) {
            half8_t Bl = *(const half8_t*)&sXl[w * 16 + lcol][quad * 8];
            acc0 = __builtin_amdgcn_mfma_f32_16x16x32_f16(Ah0, Bl, acc0, 0, 0, 0);
            acc1 = __builtin_amdgcn_mfma_f32_16x16x32_f16(Ah1, Bl, acc1, 0, 0, 0);
        }
        __syncthreads();
    }

#pragma unroll
    for (int r = 0; r < 4; ++r) {
        int m0 = tm + quad * 4 + r;
        Yb[(size_t)m0 * 1024 + tn + w * 16 + lcol]        = acc0[r] + bias[m0];
        Yb[(size_t)(m0 + 16) * 1024 + tn + w * 16 + lcol] = acc1[r] + bias[m0 + 16];
    }
}

// ---------------------------------------------------------------------------
// FUSED MFMA K+V projection (R15 version): X tile staged once, both products.
//   K: D[n][hc] = X^T·Wk^T -> khT [bh][n][hc]
//   V: D[hc][n] = Wv·X     -> vhb [bh][hc][n]
// ---------------------------------------------------------------------------
__global__ __launch_bounds__(256) void gemm_kv_fused(
    const float* __restrict__ Wk, const float* __restrict__ bk,
    const float* __restrict__ Wv, const float* __restrict__ bv,
    const float* __restrict__ X,
    _Float16* __restrict__ khT, _Float16* __restrict__ vhb)
{
    const int bz = blockIdx.z;
    const int head = blockIdx.y;
    const int tm = head * 32;
    const int tn = blockIdx.x * 64;
    const int tid = threadIdx.x;
    const int w = tid >> 6, lane = tid & 63;
    const int quad = lane >> 4, lcol = lane & 15;
    const int bh = bz * 12 + head;

    __shared__ _Float16 sWk[32][40], sWv[32][40];
    __shared__ _Float16 sXh[64][40];

    const float* Xb = X + (size_t)bz * CC * 1024;

    f4_t ak0 = {0.f, 0.f, 0.f, 0.f}, ak1 = {0.f, 0.f, 0.f, 0.f};
    f4_t av0 = {0.f, 0.f, 0.f, 0.f}, av1 = {0.f, 0.f, 0.f, 0.f};

    for (int k0 = 0; k0 < CC; k0 += 32) {
        {
            int m = tid >> 3, k4 = (tid & 7) * 4;
            float4 wk = *(const float4*)&Wk[(size_t)(tm + m) * CC + k0 + k4];
            float4 wv = *(const float4*)&Wv[(size_t)(tm + m) * CC + k0 + k4];
            half4_t hk; hk[0] = (_Float16)wk.x; hk[1] = (_Float16)wk.y;
            hk[2] = (_Float16)wk.z; hk[3] = (_Float16)wk.w;
            half4_t hv; hv[0] = (_Float16)wv.x; hv[1] = (_Float16)wv.y;
            hv[2] = (_Float16)wv.z; hv[3] = (_Float16)wv.w;
            *(half4_t*)&sWk[m][k4] = hk;
            *(half4_t*)&sWv[m][k4] = hv;
        }
        {
            int k = tid >> 3, nj = tid & 7;
            const float* xr = &Xb[(size_t)(k0 + k) * 1024 + tn + nj];
#pragma unroll
            for (int i = 0; i < 8; ++i)
                sXh[nj + 8 * i][k] = (_Float16)xr[8 * i];
        }
        __syncthreads();

        half8_t Xa = *(const half8_t*)&sXh[w * 16 + lcol][quad * 8];
        half8_t K0 = *(const half8_t*)&sWk[lcol][quad * 8];
        half8_t K1 = *(const half8_t*)&sWk[16 + lcol][quad * 8];
        half8_t V0 = *(const half8_t*)&sWv[lcol][quad * 8];
        half8_t V1 = *(const half8_t*)&sWv[16 + lcol][quad * 8];
        ak0 = __builtin_amdgcn_mfma_f32_16x16x32_f16(Xa, K0, ak0, 0, 0, 0);
        ak1 = __builtin_amdgcn_mfma_f32_16x16x32_f16(Xa, K1, ak1, 0, 0, 0);
        av0 = __builtin_amdgcn_mfma_f32_16x16x32_f16(V0, Xa, av0, 0, 0, 0);
        av1 = __builtin_amdgcn_mfma_f32_16x16x32_f16(V1, Xa, av1, 0, 0, 0);
        __syncthreads();
    }

    {
        float bk0 = bk[tm + lcol], bk1 = bk[tm + 16 + lcol];
#pragma unroll
        for (int r = 0; r < 4; ++r) {
            int n = tn + w * 16 + quad * 4 + r;
            khT[((size_t)bh * 1024 + n) * 32 + lcol]      = (_Float16)(ak0[r] + bk0);
            khT[((size_t)bh * 1024 + n) * 32 + 16 + lcol] = (_Float16)(ak1[r] + bk1);
        }
    }
    {
#pragma unroll
        for (int r = 0; r < 4; ++r) {
            int hc0 = quad * 4 + r;
            vhb[((size_t)bh * 32 + hc0) * 1024 + tn + w * 16 + lcol] =
                (_Float16)(av0[r] + bv[tm + hc0]);
            vhb[((size_t)bh * 32 + hc0 + 16) * 1024 + tn + w * 16 + lcol] =
                (_Float16)(av1[r] + bv[tm + hc0 + 16]);
        }
    }
}

// ---------------------------------------------------------------------------
// Depthwise 7x7 conv on q viewed as [12, 64, 32, 32]; zero pad 3.
// ---------------------------------------------------------------------------
__global__ __launch_bounds__(256) void dwconv_kernel(
    const float* __restrict__ q, const float* __restrict__ dww,
    const float* __restrict__ dwb, float* __restrict__ oconv)
{
    const int bc = blockIdx.x;
    const int bg = bc >> 6, c = bc & 63;
    const int b = bg / 6, g = bg % 6;
    const float* plane = q + ((size_t)b * CC + g * 64 + c) * 1024;

    __shared__ float sp[1024];
    __shared__ float sw[49];
    const int tid = threadIdx.x;
    for (int i = tid; i < 1024; i += 256) sp[i] = plane[i];
    if (tid < 49) sw[tid] = dww[c * 49 + tid];
    __syncthreads();

    const float bias = dwb[c];
    for (int i = tid; i < 1024; i += 256) {
        int y = i >> 5, x = i & 31;
        float s = 0.f;
#pragma unroll
        for (int ky = 0; ky < 7; ++ky) {
            int yy = y + ky - 3;
            if (yy < 0 || yy > 31) continue;
#pragma unroll
            for (int kx = 0; kx < 7; ++kx) {
                int xx = x + kx - 3;
                if (xx < 0 || xx > 31) continue;
                s += sp[yy * 32 + xx] * sw[ky * 7 + kx];
            }
        }
        oconv[(size_t)bc * 1024 + i] = s + bias;
    }
}

// ---------------------------------------------------------------------------
// FUSED offset + sample, 4-way channel-split (R13 version).
// ---------------------------------------------------------------------------
__global__ __launch_bounds__(256) void offset_sample_kernel(
    const float* __restrict__ oconv, const float* __restrict__ lng,
    const float* __restrict__ lnb, const float* __restrict__ pw,
    const float* __restrict__ x, float* __restrict__ pos,
    float* __restrict__ xs)
{
    const int bg = blockIdx.y;
    const int cs = blockIdx.z;
    const int px0 = blockIdx.x * 64;
    const int t = threadIdx.x;
    const int cg = t >> 6, pl = t & 63;
    const int px = px0 + pl;
    const int b = bg / 6, g = bg % 6;

    __shared__ float red[4][64];
    __shared__ float spos[64][2];

    const float* base = oconv + ((size_t)bg * 64 + cg * 16) * 1024 + px;
    float col[16];
    float s = 0.f;
#pragma unroll
    for (int i = 0; i < 16; ++i) { col[i] = base[(size_t)i * 1024]; s += col[i]; }
    red[cg][pl] = s;
    __syncthreads();
    float mu = (red[0][pl] + red[1][pl] + red[2][pl] + red[3][pl]) * (1.f / 64.f);
    float v = 0.f;
#pragma unroll
    for (int i = 0; i < 16; ++i) { float d = col[i] - mu; v += d * d; }
    __syncthreads();
    red[cg][pl] = v;
    __syncthreads();
    float inv = rsqrtf((red[0][pl] + red[1][pl] + red[2][pl] + red[3][pl]) * (1.f / 64.f) + 1e-5f);

    float oy = 0.f, ox = 0.f;
#pragma unroll
    for (int i = 0; i < 16; ++i) {
        int c = cg * 16 + i;
        float val = (col[i] - mu) * inv * lng[c] + lnb[c];
        float gl = 0.5f * val * (1.f + erff(val * 0.70710678118654752440f));
        oy += gl * pw[c];
        ox += gl * pw[64 + c];
    }
    __syncthreads();
    red[cg][pl] = oy;
    __syncthreads();
    float oyt = red[0][pl] + red[1][pl] + red[2][pl] + red[3][pl];
    __syncthreads();
    red[cg][pl] = ox;
    __syncthreads();
    if (cg == 0) {
        float oxt = red[0][pl] + red[1][pl] + red[2][pl] + red[3][pl];
        float offy = tanhf(oyt) * (2.0f / 32.0f);
        float offx = tanhf(oxt) * (2.0f / 32.0f);
        int y = px >> 5, xx = px & 31;
        float ry = ((y + 0.5f) / 32.f) * 2.f - 1.f;
        float rx = ((xx + 0.5f) / 32.f) * 2.f - 1.f;
        float py = offy + ry, pxv = offx + rx;
        spos[pl][0] = py; spos[pl][1] = pxv;
        if (cs == 0) {
            pos[((size_t)bg * 1024 + px) * 2 + 0] = py;
            pos[((size_t)bg * 1024 + px) * 2 + 1] = pxv;
        }
    }
    __syncthreads();

    float py = spos[pl][0], pxv = spos[pl][1];
    float gx = (pxv + 1.f) * 0.5f * 31.f;
    float gy = (py + 1.f) * 0.5f * 31.f;
    float x0f = floorf(gx), y0f = floorf(gy);
    float wx = gx - x0f, wy = gy - y0f;
    int x0 = (int)x0f, y0 = (int)y0f;
    float vx0 = ((unsigned)x0 <= 31u) ? 1.f : 0.f;
    float vx1 = ((unsigned)(x0 + 1) <= 31u) ? 1.f : 0.f;
    float vy0 = ((unsigned)y0 <= 31u) ? 1.f : 0.f;
    float vy1 = ((unsigned)(y0 + 1) <= 31u) ? 1.f : 0.f;
    float w00 = (1.f - wx) * (1.f - wy) * vx0 * vy0;
    float w01 = wx * (1.f - wy) * vx1 * vy0;
    float w10 = (1.f - wx) * wy * vx0 * vy1;
    float w11 = wx * wy * vx1 * vy1;
    int xc0 = min(max(x0, 0), 31), xc1 = min(max(x0 + 1, 0), 31);
    int yc0 = min(max(y0, 0), 31), yc1 = min(max(y0 + 1, 0), 31);
    int i00 = yc0 * 32 + xc0, i01 = yc0 * 32 + xc1;
    int i10 = yc1 * 32 + xc0, i11 = yc1 * 32 + xc1;

    const int c0 = cs * 16 + cg * 4;
    const float* xb = x + ((size_t)b * CC + g * 64 + c0) * 1024;
    float* xso = xs + ((size_t)b * CC + g * 64 + c0) * 1024 + px;
#pragma unroll
    for (int i = 0; i < 4; ++i) {
        const float* plane = xb + (size_t)i * 1024;
        xso[(size_t)i * 1024] = plane[i00] * w00 + plane[i01] * w01
                              + plane[i10] * w10 + plane[i11] * w11;
    }
}

// ---------------------------------------------------------------------------
// MFMA flash attention, TWO HEADS PER BLOCK (heads 2g, 2g+1 share pos ->
// identical RPE displacement geometry; compute gx/gy/wx/wy/indices ONCE,
// tap both heads' LDS tables). Transposed S^T=K·Q^T, K-split 4 waves,
// windowed RPE (35 rows, both heads), fixed-shift softmax, barrier-free
// K-loop (wave-private P slabs, one per head).
// LDS 38.7KB: srpe0 @0, srpe1 @8832, sqh @17664 (2 heads), sp @19712
// (4 waves x 2 heads x 2304B), cml @38144 (2x256B). comb0/1 alias sp.
// ---------------------------------------------------------------------------
__global__ __launch_bounds__(256) void attn_mfma_kernel(
    const float* __restrict__ q, const _Float16* __restrict__ khT,
    const _Float16* __restrict__ vhb, const float* __restrict__ pos,
    const float* __restrict__ rpe, float* __restrict__ out)
{
    const int bgp = blockIdx.y;            // 0..11 = (b, g)
    const int b = bgp / 6, g = bgp % 6;
    const int h0 = g * 2;
    const int bh0 = b * 12 + h0, bh1 = bh0 + 1;
    const int mblk = blockIdx.x * 16;
    const int tid = threadIdx.x;
    const int w = tid >> 6, lane = tid & 63;
    const int quad = lane >> 4, lcol = lane & 15;

    __shared__ __align__(16) char smem[38656];
    half2_t*  srpe0 = (half2_t*)smem;
    half2_t*  srpe1 = (half2_t*)(smem + 8832);
    _Float16* sqh   = (_Float16*)(smem + 17664);
    _Float16* spw   = (_Float16*)(smem + 19712) + w * 2304;   // h0: +0, h1: +1152
    float*    cml0  = (float*)(smem + 38144);
    float*    cml1  = (float*)(smem + 38400);
    float*    comb0 = (float*)(smem + 19712);
    float*    comb1 = (float*)(smem + 19712 + 9216);

    const float qyw = (((mblk >> 5) + 0.5f) * (1.f / 32.f)) * 2.f - 1.f;
    int r0; {
        float gy_lo = (qyw - 1.03125f) * 15.5f + 31.f;
        r0 = (int)floorf(gy_lo);
        r0 = min(max(r0, 0), 28);
    }

    {   // stage both heads' RPE windows as half2 pair tables
        const float* rp0 = rpe + (size_t)h0 * 3969;
        const float* rp1 = rp0 + 3969;
        for (int i = tid; i < 35 * 63; i += 256) {
            int y = i / 63, xx = i - y * 63;
            int gi = (r0 + y) * 63 + xx;
            float a0 = rp0[gi], b0 = (xx < 62) ? rp0[gi + 1] : 0.f;
            float a1 = rp1[gi], b1 = (xx < 62) ? rp1[gi + 1] : 0.f;
            half2_t hv0; hv0[0] = (_Float16)a0; hv0[1] = (_Float16)b0;
            half2_t hv1; hv1[0] = (_Float16)a1; hv1[1] = (_Float16)b1;
            srpe0[i] = hv0;
            srpe1[i] = hv1;
        }
    }
    {   // stage q for both heads: [head][m][hc]
        const float* qb = q + ((size_t)b * CC + h0 * 32) * 1024 + mblk;
        for (int i = tid; i < 1024; i += 256) {
            int hh = i >> 9, rem = i & 511;
            int hc = rem >> 4, m = rem & 15;
            sqh[hh * 512 + m * 32 + hc] =
                (_Float16)qb[(size_t)(hh * 32 + hc) * 1024 + m];
        }
    }
    __syncthreads();

    half8_t qf0 = *(const half8_t*)&sqh[lcol * 32 + quad * 8];
    half8_t qf1 = *(const half8_t*)&sqh[512 + lcol * 32 + quad * 8];
    const float qx = (((mblk & 31) + lcol + 0.5f) * (1.f / 32.f)) * 2.f - 1.f;

    const float2* pgv = (const float2*)(pos + (size_t)bgp * 2048);
    const _Float16* khb0 = khT + (size_t)bh0 * 1024 * 32;
    const _Float16* khb1 = khT + (size_t)bh1 * 1024 * 32;
    const _Float16* vhh0 = vhb + (size_t)bh0 * 32 * 1024;
    const _Float16* vhh1 = vhb + (size_t)bh1 * 32 * 1024;

    f4_t o00 = {0.f, 0.f, 0.f, 0.f}, o01 = {0.f, 0.f, 0.f, 0.f};
    f4_t o10 = {0.f, 0.f, 0.f, 0.f}, o11 = {0.f, 0.f, 0.f, 0.f};
    float lsum0 = 0.f, lsum1 = 0.f;

#pragma unroll 1
    for (int c = 0; c < 4; ++c) {
        const int n0 = w * 256 + c * 64;

        // prefetch K fragments for both heads
        half8_t khv0[4], khv1[4];
#pragma unroll
        for (int t = 0; t < 4; ++t) {
            size_t off = (size_t)(n0 + t * 16 + lcol) * 32 + quad * 8;
            khv0[t] = *(const half8_t*)&khb0[off];
            khv1[t] = *(const half8_t*)&khb1[off];
        }

        f4_t S0[4], S1[4];
#pragma unroll
        for (int t = 0; t < 4; ++t) {
            f4_t s0 = {0.f, 0.f, 0.f, 0.f}, s1 = {0.f, 0.f, 0.f, 0.f};
            s0 = __builtin_amdgcn_mfma_f32_16x16x32_f16(khv0[t], qf0, s0, 0, 0, 0);
            s1 = __builtin_amdgcn_mfma_f32_16x16x32_f16(khv1[t], qf1, s1, 0, 0, 0);
#pragma unroll
            for (int r = 0; r < 4; ++r) {
                int key = n0 + t * 16 + quad * 4 + r;
                float2 pp = pgv[key];
                // shared displacement geometry (identical for both heads)
                float gy = (qyw - pp.x) * 15.5f + 31.f;
                float gx = (qx  - pp.y) * 15.5f + 31.f;
                float y0f = floorf(gy), x0f = floorf(gx);
                float wy = gy - y0f, wx = gx - x0f;
                int i00 = ((int)y0f - r0) * 63 + (int)x0f;
                // head0 taps
                {
                    half2_t p0 = srpe0[i00];
                    half2_t p1 = srpe0[i00 + 63];
                    float t0 = (float)p0[0] + ((float)p0[1] - (float)p0[0]) * wx;
                    float b0 = (float)p1[0] + ((float)p1[1] - (float)p1[0]) * wx;
                    s0[r] = s0[r] * ATTN_SCALE + t0 + (b0 - t0) * wy;
                }
                // head1 taps (same indices/weights)
                {
                    half2_t p0 = srpe1[i00];
                    half2_t p1 = srpe1[i00 + 63];
                    float t1 = (float)p0[0] + ((float)p0[1] - (float)p0[0]) * wx;
                    float b1 = (float)p1[0] + ((float)p1[1] - (float)p1[0]) * wx;
                    s1[r] = s1[r] * ATTN_SCALE + t1 + (b1 - t1) * wy;
                }
            }
            S0[t] = s0; S1[t] = s1;
        }

        // prefetch V for head0 (covers exp-section latency)
        half8_t vv00[2], vv01[2];
#pragma unroll
        for (int kp = 0; kp < 2; ++kp) {
            int nb = n0 + kp * 32 + quad * 8;
            vv00[kp] = *(const half8_t*)&vhh0[(size_t)lcol * 1024 + nb];
            vv01[kp] = *(const half8_t*)&vhh0[(size_t)(16 + lcol) * 1024 + nb];
        }

        // fixed-shift exp + P stores for both heads
#pragma unroll
        for (int t = 0; t < 4; ++t) {
            float p0 = __expf(S0[t][0]), p1 = __expf(S0[t][1]);
            float p2 = __expf(S0[t][2]), p3 = __expf(S0[t][3]);
            lsum0 += (p0 + p1) + (p2 + p3);
            half4_t h;
            h[0] = (_Float16)p0; h[1] = (_Float16)p1;
            h[2] = (_Float16)p2; h[3] = (_Float16)p3;
            *(half4_t*)&spw[lcol * 72 + t * 16 + quad * 4] = h;
            float r0e = __expf(S1[t][0]), r1e = __expf(S1[t][1]);
            float r2e = __expf(S1[t][2]), r3e = __expf(S1[t][3]);
            lsum1 += (r0e + r1e) + (r2e + r3e);
            half4_t h1;
            h1[0] = (_Float16)r0e; h1[1] = (_Float16)r1e;
            h1[2] = (_Float16)r2e; h1[3] = (_Float16)r3e;
            *(half4_t*)&spw[1152 + lcol * 72 + t * 16 + quad * 4] = h1;
        }

        // PV head0 (wave-internal LDS read-back; no barrier)
#pragma unroll
        for (int kp = 0; kp < 2; ++kp) {
            half8_t pb = *(const half8_t*)&spw[lcol * 72 + kp * 32 + quad * 8];
            o00 = __builtin_amdgcn_mfma_f32_16x16x32_f16(vv00[kp], pb, o00, 0, 0, 0);
            o01 = __builtin_amdgcn_mfma_f32_16x16x32_f16(vv01[kp], pb, o01, 0, 0, 0);
        }
        // PV head1 (V loaded JIT)
#pragma unroll
        for (int kp = 0; kp < 2; ++kp) {
            int nb = n0 + kp * 32 + quad * 8;
            half8_t v0 = *(const half8_t*)&vhh1[(size_t)lcol * 1024 + nb];
            half8_t v1 = *(const half8_t*)&vhh1[(size_t)(16 + lcol) * 1024 + nb];
            half8_t pb = *(const half8_t*)&spw[1152 + lcol * 72 + kp * 32 + quad * 8];
            o10 = __builtin_amdgcn_mfma_f32_16x16x32_f16(v0, pb, o10, 0, 0, 0);
            o11 = __builtin_amdgcn_mfma_f32_16x16x32_f16(v1, pb, o11, 0, 0, 0);
        }
    }

    lsum0 += __shfl_xor(lsum0, 16); lsum0 += __shfl_xor(lsum0, 32);
    lsum1 += __shfl_xor(lsum1, 16); lsum1 += __shfl_xor(lsum1, 32);

    __syncthreads();   // all waves done with P slabs -> alias as comb0/comb1

    *(f4_t*)&comb0[(w * 16 + lcol) * 36 + quad * 4]      = o00;
    *(f4_t*)&comb0[(w * 16 + lcol) * 36 + 16 + quad * 4] = o01;
    *(f4_t*)&comb1[(w * 16 + lcol) * 36 + quad * 4]      = o10;
    *(f4_t*)&comb1[(w * 16 + lcol) * 36 + 16 + quad * 4] = o11;
    if (quad == 0) {
        cml0[w * 16 + lcol] = lsum0;
        cml1[w * 16 + lcol] = lsum1;
    }
    __syncthreads();

#pragma unroll
    for (int i = 0; i < 2; ++i) {
        int idx = tid + i * 256;
        int qq = idx >> 5, hc = idx & 31;
        {
            float L = cml0[qq] + cml0[16 + qq] + cml0[32 + qq] + cml0[48 + qq];
            float o = comb0[(0 * 16 + qq) * 36 + hc]
                    + comb0[(1 * 16 + qq) * 36 + hc]
                    + comb0[(2 * 16 + qq) * 36 + hc]
                    + comb0[(3 * 16 + qq) * 36 + hc];
            out[((size_t)b * CC + h0 * 32 + hc) * 1024 + mblk + qq] = o / L;
        }
        {
            float L = cml1[qq] + cml1[16 + qq] + cml1[32 + qq] + cml1[48 + qq];
            float o = comb1[(0 * 16 + qq) * 36 + hc]
                    + comb1[(1 * 16 + qq) * 36 + hc]
                    + comb1[(2 * 16 + qq) * 36 + hc]
                    + comb1[(3 * 16 + qq) * 36 + hc];
            out[((size_t)b * CC + (h0 + 1) * 32 + hc) * 1024 + mblk + qq] = o / L;
        }
    }
}

// ---------------------------------------------------------------------------
extern "C" void kernel_launch(void* const* d_in, const int* in_sizes, int n_in,
                              void* d_out, int out_size, void* d_ws, size_t ws_size,
                              hipStream_t stream) {
    const float* x   = (const float*)d_in[0];
    const float* Wq  = (const float*)d_in[1];
    const float* bq  = (const float*)d_in[2];
    const float* Wk  = (const float*)d_in[3];
    const float* bk  = (const float*)d_in[4];
    const float* Wv  = (const float*)d_in[5];
    const float* bv  = (const float*)d_in[6];
    const float* Wo  = (const float*)d_in[7];
    const float* bo  = (const float*)d_in[8];
    const float* dww = (const float*)d_in[9];
    const float* dwb = (const float*)d_in[10];
    const float* lng = (const float*)d_in[11];
    const float* lnb = (const float*)d_in[12];
    const float* pw  = (const float*)d_in[13];
    const float* rpe = (const float*)d_in[14];

    float* ws = (float*)d_ws;
    const size_t SZ = 786432;           // 2*384*1024 floats
    float* qbuf  = ws;
    float* xs    = ws + 1 * SZ;
    float* abuf  = ws + 2 * SZ;
    float* oconv = ws + 3 * SZ;
    _Float16* khT = (_Float16*)(ws + 4 * SZ);
    _Float16* vhb = (_Float16*)(ws + 5 * SZ);
    float* pos   = ws + 6 * SZ;

    dim3 gqo(16, 12, 2);
    gemm_wx<0><<<gqo, 256, 0, stream>>>(Wq, bq, x, qbuf);
    dwconv_kernel<<<768, 256, 0, stream>>>(qbuf, dww, dwb, oconv);
    offset_sample_kernel<<<dim3(16, 12, 4), 256, 0, stream>>>(oconv, lng, lnb, pw, x, pos, xs);
    gemm_kv_fused<<<dim3(16, 12, 2), 256, 0, stream>>>(Wk, bk, Wv, bv, xs, khT, vhb);
    attn_mfma_kernel<<<dim3(64, 12), 256, 0, stream>>>(qbuf, khT, vhb, pos, rpe, abuf);
    gemm_wx<1><<<gqo, 256, 0, stream>>>(Wo, bo, abuf, (float*)d_out);
}